// Round 5
// baseline (7531.304 us; speedup 1.0000x reference)
//
#include <hip/hip_runtime.h>
#include <hip/hip_bf16.h>
#include <math.h>

typedef unsigned short u16;
typedef __attribute__((ext_vector_type(4))) float f32x4;
typedef __attribute__((ext_vector_type(8))) short s16x8;

#define BB  512
#define TT  120
#define LAT 292
#define HH1 701
#define HH3 901
#define H1P 704
#define H3P 960
#define CH  35

// ws layout (bytes, all 256-aligned)
static const size_t O_X    = 0;                     // 512*292*4
static const size_t O_XP1  = 598016;                // 512*2112*4
static const size_t O_H1F  = 4923392;               // 2*512*704*4
static const size_t O_H2F  = 7806976;               // 2*512*704*4
static const size_t O_H3F  = 10690560;              // 2*512*960*4
static const size_t O_H1B  = 14622720;              // 2*512*704*2
static const size_t O_H2B  = 16064512;              // 2*512*704*2
static const size_t O_H3B  = 17506304;              // 2*512*960*2
static const size_t O_WHT1 = 19472384;              // 2112*704*2
static const size_t O_WIT2 = 22446080;              // 2112*704*2
static const size_t O_WHT2 = 25419776;              // 2112*704*2
static const size_t O_WIT3 = 28393472;              // 2816*704*2
static const size_t O_WHT3 = 32358400;              // 2816*960*2
static const size_t O_WOT  = 37765120;              // 64*960*2
static const size_t O_TAB  = 37888000;              // 256*4
static const size_t ZERO_BYTES = 14548992;          // O_H1F..O_H3B end

static __device__ __forceinline__ u16 f2b(float f){
  union { float f; unsigned int i; } v; v.f = f;
  unsigned int x = v.i;
  return (u16)((x + 0x7FFFu + ((x >> 16) & 1u)) >> 16);
}

// ---------------- prologue: x = selu(z @ W1 + b1) ----------------
__launch_bounds__(256)
__global__ void k_selu(const float* __restrict__ z, const float* __restrict__ W1,
                       const float* __restrict__ b1, float* __restrict__ x)
{
  int idx = blockIdx.x * 256 + threadIdx.x;
  if (idx >= BB * LAT) return;
  int b = idx / LAT, i = idx - b * LAT;
  float acc = b1[i];
  const float* zr = z + (size_t)b * LAT;
  for (int k = 0; k < LAT; ++k)
    acc += zr[k] * W1[k * LAT + i];
  const float alpha = 1.6732632423543772f, scale = 1.0507009873554805f;
  x[idx] = scale * (acc > 0.f ? acc : alpha * (expf(acc) - 1.f));
}

// ---------------- prologue: xp1 = x @ Wi1 + bi1 (f32, [512][2112]) ----------------
__launch_bounds__(256)
__global__ void k_xp1(const float* __restrict__ x, const float* __restrict__ Wi1,
                      const float* __restrict__ bi1, float* __restrict__ xp1)
{
  int nb = blockIdx.x % 9, bb = blockIdx.x / 9;
  int n = nb * 256 + threadIdx.x;
  int b0 = bb * 8;
  if (n >= 2112) return;
  if (n >= 2103) { for (int r = 0; r < 8; ++r) xp1[(size_t)(b0 + r) * 2112 + n] = 0.f; return; }
  float bias = bi1[n];
  float acc[8];
  for (int r = 0; r < 8; ++r) acc[r] = bias;
  for (int k = 0; k < LAT; ++k) {
    float w = Wi1[(size_t)k * 2103 + n];
    #pragma unroll
    for (int r = 0; r < 8; ++r) acc[r] += x[(size_t)(b0 + r) * LAT + k] * w;
  }
  for (int r = 0; r < 8; ++r) xp1[(size_t)(b0 + r) * 2112 + n] = acc[r];
}

// ---------------- prologue: WT[n][k] = bf16(W[k][n]), zero-padded ----------------
__launch_bounds__(256)
__global__ void k_transpose(const float* __restrict__ W, u16* __restrict__ WT,
                            int K, int N, int Kpad, int RowsPad)
{
  int tilesN = RowsPad / 64;
  int tk = blockIdx.x / tilesN, tn = blockIdx.x % tilesN;
  int k0 = tk * 64, n0 = tn * 64;
  __shared__ u16 lds[64][72];
  int tid = threadIdx.x;
  int nl = tid & 63, q = tid >> 6;
  for (int i = 0; i < 16; ++i) {
    int kl = q * 16 + i;
    int k = k0 + kl, n = n0 + nl;
    lds[kl][nl] = (k < K && n < N) ? f2b(W[(size_t)k * N + n]) : (u16)0;
  }
  __syncthreads();
  for (int i = 0; i < 16; ++i) {
    int rl = q * 16 + i;
    WT[(size_t)(n0 + rl) * Kpad + k0 + nl] = lds[nl][rl];
  }
}

// ---------------- prologue: 256 balanced slots, XCD-pinned, col-major locality ----
// slot p: XCD p%8, list index p/8. Items u16: L(bits12-13) r(8-10) c(0-7).
// L: 0=GRU1 1=GRU2 2=GRU3 3=OUT. Per XCD: 15 G3 singles, 11 G2 singles,
// 5 G1 pairs, 1 (G1+OUT). K-steps per slot: 52/44/44/52 (avg 48).
__global__ void k_maketab(unsigned int* __restrict__ tab)
{
  if (threadIdx.x != 0 || blockIdx.x != 0) return;
  for (int x = 0; x < 8; ++x) {
    for (int li = 0; li < 32; ++li) {
      unsigned int v;
      if (li < 15) {
        int t3 = 15 * x + li;
        v = 0xFFFF0000u | (2u << 12) | ((unsigned)(t3 % 8) << 8) | (unsigned)(t3 / 8);
      } else if (li < 26) {
        int t2 = 11 * x + (li - 15);
        v = 0xFFFF0000u | (1u << 12) | ((unsigned)(t2 % 8) << 8) | (unsigned)(t2 / 8);
      } else if (li < 31) {
        int i0 = 11 * x + 2 * (li - 26), i1 = i0 + 1;
        unsigned lo = (0u << 12) | ((unsigned)(i0 % 8) << 8) | (unsigned)(i0 / 8);
        unsigned hi = (0u << 12) | ((unsigned)(i1 % 8) << 8) | (unsigned)(i1 / 8);
        v = lo | (hi << 16);
      } else {
        int i0 = 11 * x + 10;
        unsigned lo = (0u << 12) | ((unsigned)(i0 % 8) << 8) | (unsigned)(i0 / 8);
        unsigned hi = (3u << 12) | ((unsigned)x << 8);
        v = lo | (hi << 16);
      }
      tab[x + 8 * li] = v;
    }
  }
}

// ---------------- GRU K-segment: direct global->reg, depth-3 pipeline, no LDS ----
template<int HACC>
__device__ __forceinline__ void gru_seg(
    const u16* __restrict__ A, const u16* __restrict__ W,
    int As, int Ws, int Ks, int H, int r0, int j0,
    int wr, int wc, int m16, int kg, f32x4 (&acc)[4][2][2])
{
  if (Ks <= 0) return;
  const int a0  = (r0 + wr * 32 + m16) * As + kg * 8;
  const int a1  = a0 + 16 * As;
  const int b00 = (j0 + wc * 32 + m16) * Ws + kg * 8;
  const int b01 = b00 + 16 * Ws;
  const int gh  = H * Ws;
  int4 xA0,xA1,xB00,xB01,xB10,xB11,xB20,xB21;
  int4 yA0,yA1,yB00,yB01,yB10,yB11,yB20,yB21;
  int4 zA0,zA1,zB00,zB01,zB10,zB11,zB20,zB21;
#define LD8(P, KO) do { int k_ = (KO) * 32; \
    P##A0  = *(const int4*)(A + a0  + k_); \
    P##A1  = *(const int4*)(A + a1  + k_); \
    P##B00 = *(const int4*)(W + b00 + k_); \
    P##B01 = *(const int4*)(W + b01 + k_); \
    P##B10 = *(const int4*)(W + gh + b00 + k_); \
    P##B11 = *(const int4*)(W + gh + b01 + k_); \
    P##B20 = *(const int4*)(W + 2 * gh + b00 + k_); \
    P##B21 = *(const int4*)(W + 2 * gh + b01 + k_); } while (0)
#define MM(P) do { \
    s16x8 af0 = __builtin_bit_cast(s16x8, P##A0); \
    s16x8 af1 = __builtin_bit_cast(s16x8, P##A1); \
    s16x8 g00 = __builtin_bit_cast(s16x8, P##B00); \
    s16x8 g01 = __builtin_bit_cast(s16x8, P##B01); \
    s16x8 g10 = __builtin_bit_cast(s16x8, P##B10); \
    s16x8 g11 = __builtin_bit_cast(s16x8, P##B11); \
    s16x8 g20 = __builtin_bit_cast(s16x8, P##B20); \
    s16x8 g21 = __builtin_bit_cast(s16x8, P##B21); \
    acc[0][0][0] = __builtin_amdgcn_mfma_f32_16x16x32_bf16(af0, g00, acc[0][0][0], 0, 0, 0); \
    acc[0][0][1] = __builtin_amdgcn_mfma_f32_16x16x32_bf16(af0, g01, acc[0][0][1], 0, 0, 0); \
    acc[0][1][0] = __builtin_amdgcn_mfma_f32_16x16x32_bf16(af1, g00, acc[0][1][0], 0, 0, 0); \
    acc[0][1][1] = __builtin_amdgcn_mfma_f32_16x16x32_bf16(af1, g01, acc[0][1][1], 0, 0, 0); \
    acc[1][0][0] = __builtin_amdgcn_mfma_f32_16x16x32_bf16(af0, g10, acc[1][0][0], 0, 0, 0); \
    acc[1][0][1] = __builtin_amdgcn_mfma_f32_16x16x32_bf16(af0, g11, acc[1][0][1], 0, 0, 0); \
    acc[1][1][0] = __builtin_amdgcn_mfma_f32_16x16x32_bf16(af1, g10, acc[1][1][0], 0, 0, 0); \
    acc[1][1][1] = __builtin_amdgcn_mfma_f32_16x16x32_bf16(af1, g11, acc[1][1][1], 0, 0, 0); \
    acc[HACC][0][0] = __builtin_amdgcn_mfma_f32_16x16x32_bf16(af0, g20, acc[HACC][0][0], 0, 0, 0); \
    acc[HACC][0][1] = __builtin_amdgcn_mfma_f32_16x16x32_bf16(af0, g21, acc[HACC][0][1], 0, 0, 0); \
    acc[HACC][1][0] = __builtin_amdgcn_mfma_f32_16x16x32_bf16(af1, g20, acc[HACC][1][0], 0, 0, 0); \
    acc[HACC][1][1] = __builtin_amdgcn_mfma_f32_16x16x32_bf16(af1, g21, acc[HACC][1][1], 0, 0, 0); } while (0)
  if (Ks == 1) { LD8(x, 0); MM(x); }
  else {
    LD8(x, 0); LD8(y, 1);
    int ks = 0;
    while (1) {
      if (ks + 2 < Ks) LD8(z, ks + 2);
      MM(x); if (++ks >= Ks) break;
      if (ks + 2 < Ks) LD8(x, ks + 2);
      MM(y); if (++ks >= Ks) break;
      if (ks + 2 < Ks) LD8(y, ks + 2);
      MM(z); if (++ks >= Ks) break;
    }
  }
#undef LD8
#undef MM
}

// ---------------- wavefront step kernel (grid 256, 1 slot/CU) ----------------
__launch_bounds__(256)
__global__ void k_wave(int s, const unsigned int* __restrict__ tab,
    const u16* __restrict__ WhT1, const u16* __restrict__ WiT2, const u16* __restrict__ WhT2,
    const u16* __restrict__ WiT3, const u16* __restrict__ WhT3, const u16* __restrict__ WoT,
    const float* __restrict__ xp1,
    const float* __restrict__ gbh1,
    const float* __restrict__ gbi2, const float* __restrict__ gbh2,
    const float* __restrict__ gbi3, const float* __restrict__ gbh3,
    const float* __restrict__ bo,
    float* __restrict__ h1f, u16* __restrict__ h1b,
    float* __restrict__ h2f, u16* __restrict__ h2b,
    float* __restrict__ h3f, u16* __restrict__ h3b,
    float* __restrict__ out)
{
  __shared__ __align__(16) char smraw[27648];
  const int tid  = threadIdx.x;
  const int lane = tid & 63;
  const int wave = tid >> 6;
  const int wr = wave >> 1, wc = wave & 1;
  const int m16 = lane & 15, kg = lane >> 4;
  const int row_s = tid >> 2, kc = (tid & 3) * 8;

  const unsigned int e = tab[blockIdx.x];
  const int cur = s & 1, prv = cur ^ 1;

  for (int half = 0; half < 2; ++half) {
    const unsigned int item = half ? (e >> 16) : (e & 0xFFFFu);
    if (item == 0xFFFFu) continue;
    const int L = (item >> 12) & 3;
    const int r = (item >> 8) & 7;
    const int c = item & 0xFF;
    const int t = s - L;
    if (t < 0 || t >= TT) continue;

    if (L == 3) {
      // ---- output projection + softmax for t = s-3 (LDS path, whole block) ----
      u16 (*ldsA)[40]   = (u16 (*)[40])smraw;
      u16 (*ldsBo)[40]  = (u16 (*)[40])(smraw + 5120);
      float (*ldsL)[67] = (float (*)[67])(smraw + 10240);
      const int r0 = r * 64;
      const u16* A = h3b + (size_t)prv * BB * H3P;
      f32x4 acc[2][2];
      f32x4 z4 = {0.f, 0.f, 0.f, 0.f};
      for (int a = 0; a < 2; ++a) for (int b = 0; b < 2; ++b) acc[a][b] = z4;
      for (int ks = 0; ks < H3P / 32; ++ks) {
        int k0 = ks * 32;
        *(int4*)(&ldsA[row_s][kc])  = *(const int4*)(&A[(size_t)(r0 + row_s) * H3P + k0 + kc]);
        *(int4*)(&ldsBo[row_s][kc]) = *(const int4*)(&WoT[(size_t)row_s * H3P + k0 + kc]);
        __syncthreads();
        s16x8 af[2], bfr[2];
        #pragma unroll
        for (int fm = 0; fm < 2; ++fm) af[fm] = *(const s16x8*)(&ldsA[wr * 32 + fm * 16 + m16][kg * 8]);
        #pragma unroll
        for (int fn = 0; fn < 2; ++fn) bfr[fn] = *(const s16x8*)(&ldsBo[wc * 32 + fn * 16 + m16][kg * 8]);
        #pragma unroll
        for (int fm = 0; fm < 2; ++fm)
          #pragma unroll
          for (int fn = 0; fn < 2; ++fn)
            acc[fm][fn] = __builtin_amdgcn_mfma_f32_16x16x32_bf16(af[fm], bfr[fn], acc[fm][fn], 0, 0, 0);
        __syncthreads();
      }
      #pragma unroll
      for (int fn = 0; fn < 2; ++fn) {
        int cc = wc * 32 + fn * 16 + m16;
        float bov = (cc < CH) ? bo[cc] : 0.f;
        #pragma unroll
        for (int fm = 0; fm < 2; ++fm)
          #pragma unroll
          for (int ii = 0; ii < 4; ++ii)
            ldsL[wr * 32 + fm * 16 + kg * 4 + ii][cc] = acc[fm][fn][ii] + bov;
      }
      __syncthreads();
      if (tid < 64) {
        int b = r0 + tid;
        float mx = -1e30f;
        for (int cc = 0; cc < CH; ++cc) mx = fmaxf(mx, ldsL[tid][cc]);
        float sum = 0.f;
        for (int cc = 0; cc < CH; ++cc) sum += expf(ldsL[tid][cc] - mx);
        float inv = 1.f / sum;
        size_t ob = ((size_t)b * TT + t) * CH;
        for (int cc = 0; cc < CH; ++cc) out[ob + cc] = expf(ldsL[tid][cc] - mx) * inv;
      }
      __syncthreads();
      continue;
    }

    // ---- GRU tile: 64x64, direct-load K-loop, no barriers ----
    int H, HP, Ks0, Ks1;
    const u16 *A0 = nullptr, *W0 = nullptr, *A1, *W1s;
    int As0 = 0, Ws0 = 0, As1, Ws1;
    const float *bi = nullptr, *bh;
    float *hfP, *hfC; u16 *hbC;
    if (L == 0) {
      H = HH1; HP = H1P;
      Ks0 = 0;
      Ks1 = 22; A1 = h1b + (size_t)prv * BB * H1P; As1 = H1P; W1s = WhT1; Ws1 = H1P;
      bh = gbh1;
      hfP = h1f + (size_t)prv * BB * H1P; hfC = h1f + (size_t)cur * BB * H1P; hbC = h1b + (size_t)cur * BB * H1P;
    } else if (L == 1) {
      H = HH1; HP = H1P;
      Ks0 = 22; A0 = h1b + (size_t)prv * BB * H1P; As0 = H1P; W0 = WiT2; Ws0 = H1P;
      Ks1 = 22; A1 = h2b + (size_t)prv * BB * H1P; As1 = H1P; W1s = WhT2; Ws1 = H1P;
      bi = gbi2; bh = gbh2;
      hfP = h2f + (size_t)prv * BB * H1P; hfC = h2f + (size_t)cur * BB * H1P; hbC = h2b + (size_t)cur * BB * H1P;
    } else {
      H = HH3; HP = H3P;
      Ks0 = 22; A0 = h2b + (size_t)prv * BB * H1P; As0 = H1P; W0 = WiT3; Ws0 = H1P;
      Ks1 = 30; A1 = h3b + (size_t)prv * BB * H3P; As1 = H3P; W1s = WhT3; Ws1 = H3P;
      bi = gbi3; bh = gbh3;
      hfP = h3f + (size_t)prv * BB * H3P; hfC = h3f + (size_t)cur * BB * H3P; hbC = h3b + (size_t)cur * BB * H3P;
    }
    const int r0 = r * 64, j0 = c * 64;

    f32x4 acc[4][2][2];
    {
      f32x4 z4 = {0.f, 0.f, 0.f, 0.f};
      for (int g = 0; g < 4; ++g) for (int a = 0; a < 2; ++a) for (int b = 0; b < 2; ++b) acc[g][a][b] = z4;
    }

    if (L != 0)
      gru_seg<2>(A0, W0, As0, Ws0, Ks0, H, r0, j0, wr, wc, m16, kg, acc);
    gru_seg<3>(A1, W1s, As1, Ws1, Ks1, H, r0, j0, wr, wc, m16, kg, acc);

    // ---- gate epilogue ----
    #pragma unroll
    for (int fn = 0; fn < 2; ++fn) {
      int j = j0 + wc * 32 + fn * 16 + m16;
      if (j >= H) continue;
      float bhz = bh[j], bhr = bh[H + j], bhh = bh[2 * H + j];
      float biz = 0.f, bir = 0.f, bih = 0.f;
      if (L != 0) { biz = bi[j]; bir = bi[H + j]; bih = bi[2 * H + j]; }
      #pragma unroll
      for (int fm = 0; fm < 2; ++fm) {
        #pragma unroll
        for (int ii = 0; ii < 4; ++ii) {
          int row = r0 + wr * 32 + fm * 16 + kg * 4 + ii;
          float az  = acc[0][fm][fn][ii];
          float ar  = acc[1][fm][fn][ii];
          float axh = acc[2][fm][fn][ii];
          float arh = acc[3][fm][fn][ii];
          float pz, pr, xh_, rh_;
          if (L == 0) {
            const float* xr_ = xp1 + (size_t)row * 2112;
            pz  = xr_[j] + az + bhz;
            pr  = xr_[HH1 + j] + ar + bhr;
            xh_ = xr_[2 * HH1 + j];
            rh_ = arh + bhh;
          } else {
            pz  = az + biz + bhz;
            pr  = ar + bir + bhr;
            xh_ = axh + bih;
            rh_ = arh + bhh;
          }
          float zg = 1.f / (1.f + expf(-pz));
          float rg = 1.f / (1.f + expf(-pr));
          float hh = tanhf(xh_ + rg * rh_);
          float hp = hfP[(size_t)row * HP + j];
          float hn = zg * hp + (1.f - zg) * hh;
          hfC[(size_t)row * HP + j] = hn;
          hbC[(size_t)row * HP + j] = f2b(hn);
        }
      }
    }
  }
}

// ---------------- host ----------------
extern "C" void kernel_launch(void* const* d_in, const int* in_sizes, int n_in,
                              void* d_out, int out_size, void* d_ws, size_t ws_size,
                              hipStream_t stream)
{
  const float* z    = (const float*)d_in[0];
  const float* W1   = (const float*)d_in[1];
  const float* b1   = (const float*)d_in[2];
  const float* gWi1 = (const float*)d_in[3];
  const float* gWh1 = (const float*)d_in[4];
  const float* gbi1 = (const float*)d_in[5];
  const float* gbh1 = (const float*)d_in[6];
  const float* gWi2 = (const float*)d_in[7];
  const float* gWh2 = (const float*)d_in[8];
  const float* gbi2 = (const float*)d_in[9];
  const float* gbh2 = (const float*)d_in[10];
  const float* gWi3 = (const float*)d_in[11];
  const float* gWh3 = (const float*)d_in[12];
  const float* gbi3 = (const float*)d_in[13];
  const float* gbh3 = (const float*)d_in[14];
  const float* Wo   = (const float*)d_in[15];
  const float* bo   = (const float*)d_in[16];

  char* ws = (char*)d_ws;
  float* x_f  = (float*)(ws + O_X);
  float* xp1  = (float*)(ws + O_XP1);
  float* h1f  = (float*)(ws + O_H1F);
  float* h2f  = (float*)(ws + O_H2F);
  float* h3f  = (float*)(ws + O_H3F);
  u16*   h1b  = (u16*)(ws + O_H1B);
  u16*   h2b  = (u16*)(ws + O_H2B);
  u16*   h3b  = (u16*)(ws + O_H3B);
  u16*   WhT1 = (u16*)(ws + O_WHT1);
  u16*   WiT2 = (u16*)(ws + O_WIT2);
  u16*   WhT2 = (u16*)(ws + O_WHT2);
  u16*   WiT3 = (u16*)(ws + O_WIT3);
  u16*   WhT3 = (u16*)(ws + O_WHT3);
  u16*   WoT  = (u16*)(ws + O_WOT);
  unsigned int* tab = (unsigned int*)(ws + O_TAB);

  hipMemsetAsync(ws + O_H1F, 0, ZERO_BYTES, stream);

  k_maketab<<<1, 64, 0, stream>>>(tab);
  k_selu<<<(BB * LAT + 255) / 256, 256, 0, stream>>>(z, W1, b1, x_f);
  k_xp1<<<9 * 64, 256, 0, stream>>>(x_f, gWi1, gbi1, xp1);

  k_transpose<<<11 * 33, 256, 0, stream>>>(gWh1, WhT1, 701, 2103, 704, 2112);
  k_transpose<<<11 * 33, 256, 0, stream>>>(gWi2, WiT2, 701, 2103, 704, 2112);
  k_transpose<<<11 * 33, 256, 0, stream>>>(gWh2, WhT2, 701, 2103, 704, 2112);
  k_transpose<<<11 * 44, 256, 0, stream>>>(gWi3, WiT3, 701, 2703, 704, 2816);
  k_transpose<<<15 * 44, 256, 0, stream>>>(gWh3, WhT3, 901, 2703, 960, 2816);
  k_transpose<<<15 * 1, 256, 0, stream>>>(Wo, WoT, 901, 35, 960, 64);

  for (int s = 0; s < TT + 3; ++s)
    k_wave<<<256, 256, 0, stream>>>(s, tab, WhT1, WiT2, WhT2, WiT3, WhT3, WoT, xp1,
                                    gbh1, gbi2, gbh2, gbi3, gbh3, bo,
                                    h1f, h1b, h2f, h2b, h3f, h3b, (float*)d_out);
}